// Round 1
// baseline (1513.013 us; speedup 1.0000x reference)
//
#include <hip/hip_runtime.h>
#include <cstdint>
#include <cstddef>

typedef __bf16 bf16_t;
typedef __bf16 bf16x8 __attribute__((ext_vector_type(8)));
typedef __bf16 bf16x4 __attribute__((ext_vector_type(4)));
typedef float floatx4 __attribute__((ext_vector_type(4)));
typedef float f32x2 __attribute__((ext_vector_type(2)));

// ---------------------------------------------------------------- helpers
__device__ __forceinline__ void async16(const bf16_t* g, bf16_t* l) {
  __builtin_amdgcn_global_load_lds(
      (const __attribute__((address_space(1))) unsigned int*)g,
      (__attribute__((address_space(3))) unsigned int*)l, 16, 0, 0);
}

template<int N>
__device__ __forceinline__ float rowror(float x) {
  return __int_as_float(__builtin_amdgcn_update_dpp(
      0, __float_as_int(x), 0x120 | N, 0xf, 0xf, false));
}
// sum across 16-lane DPP row (all lanes get total) — rotate reduction
__device__ __forceinline__ float rowsum16(float x) {
  x += rowror<8>(x);
  x += rowror<4>(x);
  x += rowror<2>(x);
  x += rowror<1>(x);
  return x;
}

__device__ __forceinline__ f32x2 bf2f(unsigned u) {
  f32x2 r;
  r[0] = __uint_as_float(u << 16);
  r[1] = __uint_as_float(u & 0xffff0000u);
  return r;
}

__device__ __forceinline__ float siluf(float x) { return x / (1.f + __expf(-x)); }

// ---------------------------------------------------------------- fp32 -> bf16
__global__ __launch_bounds__(256) void k_cvt(const float* __restrict__ in,
                                             bf16_t* __restrict__ out, int n4) {
  int i = blockIdx.x * 256 + threadIdx.x;
  if (i >= n4) return;
  const float4 f = ((const float4*)in)[i];
  bf16x4 r;
  r[0] = (bf16_t)f.x; r[1] = (bf16_t)f.y; r[2] = (bf16_t)f.z; r[3] = (bf16_t)f.w;
  ((bf16x4*)out)[i] = r;
}

// W_b (32x2048) rows 0..31, W_a rows 32..63, zeros rows 64..127
__global__ __launch_bounds__(256) void k_build_wba(const float* __restrict__ wb,
                                                   const float* __restrict__ wa,
                                                   bf16_t* __restrict__ out) {
  int i = blockIdx.x * 256 + threadIdx.x;  // 65536 threads (128*2048/4)
  int e = i * 4;
  int row = e >> 11;
  int col = e & 2047;
  float4 f = make_float4(0.f, 0.f, 0.f, 0.f);
  if (row < 32)      f = *(const float4*)&wb[row * 2048 + col];
  else if (row < 64) f = *(const float4*)&wa[(row - 32) * 2048 + col];
  bf16x4 r;
  r[0] = (bf16_t)f.x; r[1] = (bf16_t)f.y; r[2] = (bf16_t)f.z; r[3] = (bf16_t)f.w;
  *(bf16x4*)&out[e] = r;
}

// ---------------------------------------------------------------- GEMM (m97-style)
// C[M,N] = A[M,K] @ B[N,K]^T, bf16 in, fp32 accum. 128x128 tile, BK=32,
// 256 threads (4 waves, each 64x64 as 4x4 of 16x16 mfma tiles).
template<bool OUT_BF16>
__global__ __launch_bounds__(256) void gemm_bt(const bf16_t* __restrict__ A,
                                               const bf16_t* __restrict__ B,
                                               void* __restrict__ Cout,
                                               int M, int N, int K) {
  __shared__ __align__(16) bf16_t As[4096];
  __shared__ __align__(16) bf16_t Bs[4096];
  const int tid  = threadIdx.x;
  const int lane = tid & 63;
  const int wave = tid >> 6;
  const int quad = lane >> 4;
  const int l16  = lane & 15;
  const int wr   = (wave >> 1) * 64;
  const int wc   = (wave & 1) * 64;
  const int m0   = blockIdx.y * 128;
  const int n0   = blockIdx.x * 128;
  const int ra   = tid >> 2;
  const int ca   = (tid & 3) * 8;

  const bf16_t* gA = A + (size_t)(m0 + ra) * K + ca;
  const bf16_t* gB = B + (size_t)(n0 + ra) * K + ca;
  bf16_t* lA = &As[tid * 8];
  bf16_t* lB = &Bs[tid * 8];

  floatx4 acc[4][4] = {};

  for (int k0 = 0; k0 < K; k0 += 32) {
    __syncthreads();                 // prior iter's LDS reads done
    async16(gA + k0, lA);
    async16(gA + k0 + (size_t)64 * K, lA + 2048);
    async16(gB + k0, lB);
    async16(gB + k0 + (size_t)64 * K, lB + 2048);
    __syncthreads();                 // vmcnt drained by compiler before barrier
    bf16x8 af[4], bfr[4];
#pragma unroll
    for (int i = 0; i < 4; ++i) {
      af[i]  = *(const bf16x8*)&As[(wr + i * 16 + l16) * 32 + quad * 8];
      bfr[i] = *(const bf16x8*)&Bs[(wc + i * 16 + l16) * 32 + quad * 8];
    }
#pragma unroll
    for (int mi = 0; mi < 4; ++mi)
#pragma unroll
      for (int ni = 0; ni < 4; ++ni)
        acc[mi][ni] = __builtin_amdgcn_mfma_f32_16x16x32_bf16(
            af[mi], bfr[ni], acc[mi][ni], 0, 0, 0);
  }

  // C/D layout (verified m89/m91): col = lane&15, row = quad*4 + reg
#pragma unroll
  for (int mi = 0; mi < 4; ++mi) {
#pragma unroll
    for (int ni = 0; ni < 4; ++ni) {
      const int row = m0 + wr + mi * 16 + quad * 4;
      const int col = n0 + wc + ni * 16 + l16;
#pragma unroll
      for (int r = 0; r < 4; ++r) {
        if (OUT_BF16)
          ((bf16_t*)Cout)[(size_t)(row + r) * N + col] = (bf16_t)acc[mi][ni][r];
        else
          ((float*)Cout)[(size_t)(row + r) * N + col] = acc[mi][ni][r];
      }
    }
  }
}

// ---------------------------------------------------------------- beta / g
__global__ __launch_bounds__(256) void k_betag(const float* __restrict__ cba,
                                               const float* __restrict__ A_log,
                                               const float* __restrict__ dtb,
                                               float* __restrict__ beta,
                                               float* __restrict__ g) {
  int i = blockIdx.x * 256 + threadIdx.x;  // T*32 = 131072
  int t = i >> 5, h = i & 31;
  float b = cba[t * 128 + h];
  float a = cba[t * 128 + 32 + h];
  beta[i] = 1.f / (1.f + __expf(-b));
  float x = a + dtb[h];
  float sp = (x > 20.f) ? x : log1pf(__expf(x));
  g[i] = -__expf(A_log[h]) * sp;
}

// ---------------------------------------------------------------- conv4 + silu + l2norm
// grid (64 groups, T). block 128 = one head's 128 channels.
__global__ __launch_bounds__(128) void k_conv(const bf16_t* __restrict__ mixed,
                                              const float* __restrict__ cw,
                                              bf16_t* __restrict__ qo,
                                              bf16_t* __restrict__ ko,
                                              bf16_t* __restrict__ vo) {
  const int t = blockIdx.y;
  const int grp = blockIdx.x;
  const int d = threadIdx.x;
  const int c = grp * 128 + d;
  const float4 wv = *(const float4*)&cw[c * 4];
  float acc = 0.f;
#pragma unroll
  for (int i = 0; i < 4; ++i) {
    int tt = t - 3 + i;
    if (tt >= 0) acc += ((const float*)&wv)[i] * (float)mixed[(size_t)tt * 8192 + c];
  }
  float val = siluf(acc);
  if (grp < 32) {  // q or k head: l2-normalize over 128 dims
    __shared__ float red[2];
    float s = val * val;
#pragma unroll
    for (int m = 1; m < 64; m <<= 1) s += __shfl_xor(s, m);
    if ((threadIdx.x & 63) == 0) red[threadIdx.x >> 6] = s;
    __syncthreads();
    float r = rsqrtf(red[0] + red[1] + 1e-6f);
    if (grp < 16)
      qo[((size_t)t * 16 + grp) * 128 + d] = (bf16_t)(val * r * 0.08838834764831845f); // *DK^-0.5 folded
    else
      ko[((size_t)t * 16 + grp - 16) * 128 + d] = (bf16_t)(val * r);
  } else {
    vo[((size_t)t * 32 + grp - 32) * 128 + d] = (bf16_t)val;
  }
}

// ---------------------------------------------------------------- gated delta scan
// grid = 32 heads * 8 col-groups; block 256 = 16 cols x 16 k-segs (8 rows each).
__global__ __launch_bounds__(256) void k_scan(const bf16_t* __restrict__ qg,
                                              const bf16_t* __restrict__ kg,
                                              const bf16_t* __restrict__ vg,
                                              const float* __restrict__ betap,
                                              const float* __restrict__ gp,
                                              float* __restrict__ o) {
  const int h = blockIdx.x & 31;
  const int colg = blockIdx.x >> 5;
  const int kh = h >> 1;           // grouped q/k heads (rep=2)
  const int tid = threadIdx.x;
  const int seg = tid & 15;        // DPP row
  const int col_l = tid >> 4;      // 0..15

  __shared__ float ls_k[32][128];
  __shared__ float ls_q[32][128];
  __shared__ float ls_v[32][16];
  __shared__ float ls_o[32][16];
  __shared__ float ls_g[32];
  __shared__ float ls_b[32];

  f32x2 S[4] = {{0.f, 0.f}, {0.f, 0.f}, {0.f, 0.f}, {0.f, 0.f}};  // rows seg*8..+7

  for (int t0 = 0; t0 < 4096; t0 += 32) {
    __syncthreads();
    // stage 32 steps of k,q (fp32 in LDS), v cols, exp(g), beta
#pragma unroll
    for (int p = 0; p < 2; ++p) {
      const int idx = p * 2048 + tid * 8;
      const int r = idx >> 7, c = idx & 127;
      const uint4 kr = *(const uint4*)&kg[((size_t)(t0 + r) * 16 + kh) * 128 + c];
      const uint4 qr = *(const uint4*)&qg[((size_t)(t0 + r) * 16 + kh) * 128 + c];
      *(f32x2*)&ls_k[r][c + 0] = bf2f(kr.x);
      *(f32x2*)&ls_k[r][c + 2] = bf2f(kr.y);
      *(f32x2*)&ls_k[r][c + 4] = bf2f(kr.z);
      *(f32x2*)&ls_k[r][c + 6] = bf2f(kr.w);
      *(f32x2*)&ls_q[r][c + 0] = bf2f(qr.x);
      *(f32x2*)&ls_q[r][c + 2] = bf2f(qr.y);
      *(f32x2*)&ls_q[r][c + 4] = bf2f(qr.z);
      *(f32x2*)&ls_q[r][c + 6] = bf2f(qr.w);
    }
    if (tid < 64) {
      const int r = tid >> 1, c = (tid & 1) * 8;
      const uint4 vr = *(const uint4*)&vg[((size_t)(t0 + r) * 32 + h) * 128 + colg * 16 + c];
      *(f32x2*)&ls_v[r][c + 0] = bf2f(vr.x);
      *(f32x2*)&ls_v[r][c + 2] = bf2f(vr.y);
      *(f32x2*)&ls_v[r][c + 4] = bf2f(vr.z);
      *(f32x2*)&ls_v[r][c + 6] = bf2f(vr.w);
    }
    if (tid < 32) {
      ls_g[tid] = __expf(gp[(size_t)(t0 + tid) * 32 + h]);
      ls_b[tid] = betap[(size_t)(t0 + tid) * 32 + h];
    }
    __syncthreads();

#pragma unroll 4
    for (int i = 0; i < 32; ++i) {
      const float dg = ls_g[i];
      const float bt = ls_b[i];
      const float vv = ls_v[i][col_l];
      const f32x2* kp = (const f32x2*)&ls_k[i][seg * 8];
      const f32x2* qp = (const f32x2*)&ls_q[i][seg * 8];
      f32x2 k2[4], q2[4];
#pragma unroll
      for (int j = 0; j < 4; ++j) { k2[j] = kp[j]; q2[j] = qp[j]; }
      // kv readout against decayed state: kv = dg * sum(k*S)
      f32x2 pa = k2[0] * S[0] + k2[1] * S[1];
      f32x2 pb = k2[2] * S[2] + k2[3] * S[3];
      float part = rowsum16(pa[0] + pa[1] + pb[0] + pb[1]);
      const float delta = (vv - dg * part) * bt;
      const f32x2 dg2 = {dg, dg};
      const f32x2 de2 = {delta, delta};
#pragma unroll
      for (int j = 0; j < 4; ++j) S[j] = S[j] * dg2 + k2[j] * de2;
      f32x2 oa = q2[0] * S[0] + q2[1] * S[1];
      f32x2 ob = q2[2] * S[2] + q2[3] * S[3];
      float op = rowsum16(oa[0] + oa[1] + ob[0] + ob[1]);
      if (seg == 0) ls_o[i][col_l] = op;   // q pre-scaled by DK^-0.5
    }
    __syncthreads();
    {  // coalesced o flush for the chunk
      const int idx = tid * 2;
      const int r = idx >> 4, c = idx & 15;
      *(f32x2*)&o[((size_t)(t0 + r) * 32 + h) * 128 + colg * 16 + c] =
          *(const f32x2*)&ls_o[r][c];
    }
  }
}

// ---------------------------------------------------------------- RMSNorm * silu(z) gate
// grid (32 heads, T). block 64 (one wave), 2 elems/thread.
__global__ __launch_bounds__(64) void k_gate(const float* __restrict__ o,
                                             const bf16_t* __restrict__ z,
                                             const float* __restrict__ nw,
                                             bf16_t* __restrict__ y) {
  const int h = blockIdx.x, t = blockIdx.y, l = threadIdx.x;
  const float* orow = o + ((size_t)t * 32 + h) * 128;
  float o0 = orow[l], o1 = orow[l + 64];
  float s = o0 * o0 + o1 * o1;
#pragma unroll
  for (int m = 1; m < 64; m <<= 1) s += __shfl_xor(s, m);
  float r = rsqrtf(s * (1.f / 128.f) + 1e-6f);
  const bf16_t* zrow = z + (size_t)t * 4096 + h * 128;
  float z0 = (float)zrow[l], z1 = (float)zrow[l + 64];
  bf16_t* yrow = y + (size_t)t * 4096 + h * 128;
  yrow[l]      = (bf16_t)(o0 * r * nw[l] * siluf(z0));
  yrow[l + 64] = (bf16_t)(o1 * r * nw[l + 64] * siluf(z1));
}

// ---------------------------------------------------------------- launch
extern "C" void kernel_launch(void* const* d_in, const int* in_sizes, int n_in,
                              void* d_out, int out_size, void* d_ws, size_t ws_size,
                              hipStream_t stream) {
  const float* hidden = (const float*)d_in[0];
  const float* W_qkv  = (const float*)d_in[1];
  const float* W_z    = (const float*)d_in[2];
  const float* W_b    = (const float*)d_in[3];
  const float* W_a    = (const float*)d_in[4];
  const float* conv_w = (const float*)d_in[5];
  const float* dt_b   = (const float*)d_in[6];
  const float* A_log  = (const float*)d_in[7];
  const float* norm_w = (const float*)d_in[8];
  const float* W_out  = (const float*)d_in[9];
  float* out = (float*)d_out;

  char* w = (char*)d_ws;
  const size_t MB = 1024 * 1024;
  bf16_t* hs    = (bf16_t*)(w + 0 * MB);    // 16 MiB  hidden bf16
  bf16_t* wqkv  = (bf16_t*)(w + 16 * MB);   // 32 MiB  (reused as y later)
  bf16_t* ybuf  = wqkv;
  bf16_t* wz    = (bf16_t*)(w + 48 * MB);   // 16 MiB
  bf16_t* wout  = (bf16_t*)(w + 64 * MB);   // 16 MiB
  bf16_t* wba   = (bf16_t*)(w + 80 * MB);   // 0.5 MiB (padded to 128 rows)
  bf16_t* mixed = (bf16_t*)(w + 81 * MB);   // 64 MiB  (reused as o fp32)
  float*  obuf  = (float*)mixed;
  bf16_t* zbuf  = (bf16_t*)(w + 145 * MB);  // 32 MiB
  float*  cba   = (float*)(w + 177 * MB);   // 2 MiB
  bf16_t* qb    = (bf16_t*)(w + 179 * MB);  // 16 MiB
  bf16_t* kb    = (bf16_t*)(w + 195 * MB);  // 16 MiB
  bf16_t* vb    = (bf16_t*)(w + 211 * MB);  // 32 MiB
  float*  betab = (float*)(w + 243 * MB);   // 0.5 MiB
  float*  gbuf  = (float*)(w + 244 * MB);   // 0.5 MiB

  // converts
  k_cvt<<<8192, 256, 0, stream>>>(hidden, hs, 2097152);
  k_cvt<<<16384, 256, 0, stream>>>(W_qkv, wqkv, 4194304);
  k_cvt<<<8192, 256, 0, stream>>>(W_z, wz, 2097152);
  k_cvt<<<8192, 256, 0, stream>>>(W_out, wout, 2097152);
  k_build_wba<<<256, 256, 0, stream>>>(W_b, W_a, wba);

  // projections
  gemm_bt<true><<<dim3(64, 32), 256, 0, stream>>>(hs, wqkv, mixed, 4096, 8192, 2048);
  gemm_bt<true><<<dim3(32, 32), 256, 0, stream>>>(hs, wz, zbuf, 4096, 4096, 2048);
  gemm_bt<false><<<dim3(1, 32), 256, 0, stream>>>(hs, wba, cba, 4096, 128, 2048);
  k_betag<<<512, 256, 0, stream>>>(cba, A_log, dt_b, betab, gbuf);

  // conv + silu + l2norm + split
  k_conv<<<dim3(64, 4096), 128, 0, stream>>>(mixed, conv_w, qb, kb, vb);

  // sequential gated delta scan (o overwrites mixed region — conv already consumed it)
  k_scan<<<256, 256, 0, stream>>>(qb, kb, vb, betab, gbuf, obuf);

  // norm + gate, then output projection
  k_gate<<<dim3(32, 4096), 64, 0, stream>>>(obuf, zbuf, norm_w, ybuf);
  gemm_bt<false><<<dim3(16, 32), 256, 0, stream>>>(ybuf, wout, out, 4096, 2048, 4096);
}